// Round 4
// baseline (247.847 us; speedup 1.0000x reference)
//
#include <hip/hip_runtime.h>
#include <hip/hip_bf16.h>
#include <math.h>

typedef __bf16 bf16x8 __attribute__((ext_vector_type(8)));
typedef float f32x4 __attribute__((ext_vector_type(4)));
typedef unsigned short u16x8 __attribute__((ext_vector_type(8)));
typedef unsigned short u16x4 __attribute__((ext_vector_type(4)));

// ---- problem constants ----
// T=1024, B=4, H=16, D=64, E=1024, M = T*B = 4096 (row m = t*4 + b)

// ws layout, element offsets (ushort elements)
#define OFF_XQ   0u          // 4096x1024 bf16
#define OFF_XK   4194304u
#define OFF_XV   8388608u
#define OFF_WQ   12582912u   // 1024x1024 bf16
#define OFF_WK   13631488u
#define OFF_WV   14680064u
#define OFF_WO   15728640u
#define OFF_QR   16777216u   // [b][h][t][d] bf16 (rope'd, Q pre-scaled by 0.125)
#define OFF_KR   20971520u
#define OFF_VROW 25165824u   // [b][h][t][d] bf16
#define OFF_VT   29360128u   // [b][h][d][t] bf16
#define OFF_AO   33554432u   // [m=q*4+b][e=h*64+d] bf16
#define OFF_MW   37748736u   // 65536 x u64 mask bits (512 KB), 8B aligned

static __device__ __forceinline__ unsigned short f2bf(float f){
  unsigned u = __builtin_bit_cast(unsigned, f);
  u += 0x7FFFu + ((u >> 16) & 1u);           // RNE
  return (unsigned short)(u >> 16);
}

static __device__ __forceinline__ f32x4 mfma16(bf16x8 a, bf16x8 b, f32x4 c){
  return __builtin_amdgcn_mfma_f32_16x16x32_bf16(a, b, c, 0, 0, 0);
}

// async global->LDS, 16B per lane (dest = wave-uniform base + lane*16)
static __device__ __forceinline__ void glds16(const unsigned short* g, unsigned short* l){
  __builtin_amdgcn_global_load_lds(
      (const __attribute__((address_space(1))) unsigned int*)g,
      (__attribute__((address_space(3))) unsigned int*)l, 16, 0, 0);
}

// -------- fp32 -> bf16 conversion of all inputs into ws (contiguous) --------
__global__ __launch_bounds__(256) void cvt_all(
    const float* __restrict__ q, const float* __restrict__ k, const float* __restrict__ v,
    const float* __restrict__ qw, const float* __restrict__ kw, const float* __restrict__ vw,
    const float* __restrict__ ow, unsigned short* __restrict__ ws)
{
  size_t e = ((size_t)blockIdx.x * 256 + threadIdx.x) * 4;
  const float* s;
  if      (e < 4194304u)  { s = q  + e; }
  else if (e < 8388608u)  { s = k  + (e - 4194304u); }
  else if (e < 12582912u) { s = v  + (e - 8388608u); }
  else if (e < 13631488u) { s = qw + (e - 12582912u); }
  else if (e < 14680064u) { s = kw + (e - 13631488u); }
  else if (e < 15728640u) { s = vw + (e - 14680064u); }
  else                    { s = ow + (e - 15728640u); }
  float4 f = *(const float4*)s;
  u16x4 o;
  o[0] = f2bf(f.x); o[1] = f2bf(f.y); o[2] = f2bf(f.z); o[3] = f2bf(f.w);
  *(u16x4*)(ws + e) = o;
}

// -------- pack (am | kpm) into bitmask words: mw[(b*1024+q)*16 + w], bit j = key (w*64+j) masked --------
__global__ __launch_bounds__(256) void pack_mask(
    const int* __restrict__ am, const int* __restrict__ kpm, unsigned long long* __restrict__ mw)
{
  int idx = blockIdx.x * 256 + threadIdx.x;       // 65536 total
  int w = idx & 15, q = (idx >> 4) & 1023, b = idx >> 14;
  const int* ap = am + ((size_t)(b*1024 + q))*1024 + w*64;
  const int* kp = kpm + b*1024 + w*64;
  unsigned long long bits = 0ull;
#pragma unroll
  for (int j = 0; j < 64; j += 4){
    int4 a = *(const int4*)(ap + j);
    int4 c = *(const int4*)(kp + j);
    unsigned long long m =
        (unsigned long long)(((a.x | c.x) != 0) ? 1 : 0)
      | ((unsigned long long)(((a.y | c.y) != 0) ? 1 : 0) << 1)
      | ((unsigned long long)(((a.z | c.z) != 0) ? 1 : 0) << 2)
      | ((unsigned long long)(((a.w | c.w) != 0) ? 1 : 0) << 3);
    bits |= (m << j);
  }
  mw[idx] = bits;
}

// -------- GEMM: C[m][n] = sum_k A[m][k] * W[n][k]   (M=4096, N=1024, K=1024) --------
// 2-ahead glds pipeline, 4 LDS buffers, raw s_barrier + counted vmcnt (T3/T4).
// mode 0: outF fp32; mode 1: RoPE (acc*oscale) -> [b][h][t][d] bf16; mode 2: plain -> [b][h][t][d] bf16
__global__ __launch_bounds__(256) void gemm_bt(
    const unsigned short* __restrict__ A, const unsigned short* __restrict__ W,
    float* __restrict__ outF, unsigned short* __restrict__ outB, int mode, float oscale)
{
  const int tid = threadIdx.x;
  const int lane = tid & 63, wave = tid >> 6;
  const int wr = wave >> 1, wc = wave & 1;
  const int l16 = lane & 15, lg = lane >> 4;
  const int m0 = blockIdx.y * 128, n0 = blockIdx.x * 128;

  __shared__ unsigned short As[4][4096];
  __shared__ unsigned short Bs[4][4096];

  f32x4 acc[4][4];
#pragma unroll
  for (int i = 0; i < 4; ++i)
#pragma unroll
    for (int j = 0; j < 4; ++j)
      acc[i][j] = (f32x4){0.f, 0.f, 0.f, 0.f};

  const int r0 = tid >> 2;           // 0..63
  const int c0 = (tid & 3) * 8;      // 0,8,16,24
  const unsigned short* Ap = A + (size_t)(m0 + r0) * 1024 + c0;
  const unsigned short* Wp = W + (size_t)(n0 + r0) * 1024 + c0;

#define STG(buf, kt) do{ \
    glds16(Ap + (kt)*32,         &As[buf][(size_t)tid*8]); \
    glds16(Ap + 65536 + (kt)*32, &As[buf][2048 + (size_t)tid*8]); \
    glds16(Wp + (kt)*32,         &Bs[buf][(size_t)tid*8]); \
    glds16(Wp + 65536 + (kt)*32, &Bs[buf][2048 + (size_t)tid*8]); }while(0)

  STG(0, 0);
  STG(1, 1);

  for (int kt = 0; kt < 32; ++kt){
    if (kt < 30){
      STG((kt + 2) & 3, kt + 2);
      asm volatile("s_waitcnt vmcnt(8)" ::: "memory");   // tile kt's 4 loads retired
    } else if (kt == 30){
      asm volatile("s_waitcnt vmcnt(4)" ::: "memory");
    } else {
      asm volatile("s_waitcnt vmcnt(0)" ::: "memory");
    }
    __builtin_amdgcn_sched_barrier(0);
    __builtin_amdgcn_s_barrier();                        // all waves' tile-kt loads done
    __builtin_amdgcn_sched_barrier(0);
    const unsigned short* Ab = As[kt & 3];
    const unsigned short* Bb = Bs[kt & 3];
    bf16x8 af[4], bfr[4];
#pragma unroll
    for (int mt = 0; mt < 4; ++mt) af[mt]  = *(const bf16x8*)&Ab[(wr*64 + mt*16 + l16)*32 + lg*8];
#pragma unroll
    for (int nt = 0; nt < 4; ++nt) bfr[nt] = *(const bf16x8*)&Bb[(wc*64 + nt*16 + l16)*32 + lg*8];
#pragma unroll
    for (int mt = 0; mt < 4; ++mt)
#pragma unroll
      for (int nt = 0; nt < 4; ++nt)
        acc[mt][nt] = mfma16(af[mt], bfr[nt], acc[mt][nt]);
  }
#undef STG

  if (mode == 0){
#pragma unroll
    for (int mt = 0; mt < 4; ++mt)
#pragma unroll
      for (int nt = 0; nt < 4; ++nt)
#pragma unroll
        for (int r = 0; r < 4; ++r){
          int m = m0 + wr*64 + mt*16 + lg*4 + r;
          int n = n0 + wc*64 + nt*16 + l16;
          outF[(size_t)m*1024 + n] = acc[mt][nt][r];
        }
  } else if (mode == 2){
#pragma unroll
    for (int mt = 0; mt < 4; ++mt)
#pragma unroll
      for (int nt = 0; nt < 4; ++nt)
#pragma unroll
        for (int r = 0; r < 4; ++r){
          int m = m0 + wr*64 + mt*16 + lg*4 + r;
          int n = n0 + wc*64 + nt*16 + l16;
          int t = m >> 2, bi = m & 3, h = n >> 6, d = n & 63;
          outB[(((size_t)(bi*16 + h))*1024 + t)*64 + d] = f2bf(acc[mt][nt][r]);
        }
  } else { // mode 1: RoPE.  acc pair (nt, nt+2) holds (x1, x2) for d and d+32.
#pragma unroll
    for (int mt = 0; mt < 4; ++mt){
      int mbase = m0 + wr*64 + mt*16 + lg*4;   // multiple of 4 -> b = r, t fixed
      int t = mbase >> 2;
#pragma unroll
      for (int nt = 0; nt < 2; ++nt){
        int n = n0 + wc*64 + nt*16 + l16;
        int h = n >> 6, d = n & 31;
        float theta = expf((float)d * -0.28782313662425575f);  // -ln(10000)/32
        float ang = (float)t * theta;
        float sv = sinf(ang), cv = cosf(ang);
#pragma unroll
        for (int r = 0; r < 4; ++r){
          float x1 = acc[mt][nt][r]     * oscale;
          float x2 = acc[mt][nt + 2][r] * oscale;
          float o1 = x1*cv - x2*sv;
          float o2 = x1*sv + x2*cv;
          size_t ob = (((size_t)(r*16 + h))*1024 + t)*64;   // b = r
          outB[ob + d]      = f2bf(o1);
          outB[ob + d + 32] = f2bf(o2);
        }
      }
    }
  }
}

// -------- V transpose per head: Vrow[b][h][t][d] -> Vt[b][h][d][t] --------
__global__ __launch_bounds__(256) void vtrans(
    const unsigned short* __restrict__ Vrow, unsigned short* __restrict__ Vt)
{
  const int bh = blockIdx.y;
  const int t0 = blockIdx.x * 64;
  const unsigned short* src = Vrow + (size_t)bh*65536 + (size_t)t0*64;
  unsigned short* dst = Vt + (size_t)bh*65536 + t0;
  __shared__ unsigned short tile[64][65];
  const int tid = threadIdx.x;
#pragma unroll
  for (int i = 0; i < 16; ++i){
    int idx = tid + i*256;
    int r = idx >> 6, c = idx & 63;
    tile[r][c] = src[r*64 + c];
  }
  __syncthreads();
#pragma unroll
  for (int i = 0; i < 16; ++i){
    int idx = tid + i*256;
    int d = idx >> 6, c = idx & 63;
    dst[(size_t)d*1024 + c] = tile[c][d];
  }
}

// -------- flash attention v4: XCD-pinned heads, K+mask reg-dbuf, max-free softmax --------
// grid = 1024 linear blocks; wg&7 selects the head-group (pins all 16 q-tiles of a
// head to one XCD under round-robin dispatch -> K/V re-reads become L2 hits).
// Q pre-scaled by 0.125; mask via bit words mw[(b*1024+q)*16 + kt]
__global__ __launch_bounds__(256) void attn_kernel(
    const unsigned short* __restrict__ Qr, const unsigned short* __restrict__ Kr,
    const unsigned short* __restrict__ Vt, const unsigned long long* __restrict__ mw,
    unsigned short* __restrict__ AO)
{
  const int tid = threadIdx.x;
  const int lane = tid & 63, w = tid >> 6;
  const int l16 = lane & 15, lg = lane >> 4;
  const int wg = blockIdx.x;
  const int xcd = wg & 7, j = wg >> 3;
  const int bh = xcd * 8 + (j & 7);          // heads xcd*8 .. xcd*8+7 stay on XCD xcd
  const int qt = j >> 3;                     // 0..15
  const int b = bh >> 4, h = bh & 15;
  const int q0 = qt * 64 + w * 16;
  const size_t hb = (size_t)bh * 65536;
  const unsigned long long* mwp = mw + (size_t)b * 16384 + (size_t)(q0 + lg*4) * 16;

  __shared__ unsigned short Plds[4*1024];
  unsigned short* Pw = Plds + w*1024;          // wave-private 16x64

  bf16x8 qf0 = *(const bf16x8*)&Qr[hb + (size_t)(q0 + l16)*64 + lg*8];
  bf16x8 qf1 = *(const bf16x8*)&Qr[hb + (size_t)(q0 + l16)*64 + 32 + lg*8];

  f32x4 O[4];
  float ls[4] = {0.f, 0.f, 0.f, 0.f};
#pragma unroll
  for (int nd = 0; nd < 4; ++nd) O[nd] = (f32x4){0.f, 0.f, 0.f, 0.f};

  bf16x8 kA[4][2], kB[4][2];
  unsigned long long mA[4], mB[4];

  auto KLD = [&](int kb, bf16x8 (&kf)[4][2]){
#pragma unroll
    for (int nk = 0; nk < 4; ++nk){
      kf[nk][0] = *(const bf16x8*)&Kr[hb + (size_t)(kb + nk*16 + l16)*64 + lg*8];
      kf[nk][1] = *(const bf16x8*)&Kr[hb + (size_t)(kb + nk*16 + l16)*64 + 32 + lg*8];
    }
  };
  auto MLD = [&](int kt, unsigned long long (&m)[4]){
#pragma unroll
    for (int r = 0; r < 4; ++r) m[r] = mwp[r*16 + kt];
  };

  auto PHASE = [&](int kt, bf16x8 (&kc)[4][2], bf16x8 (&kn)[4][2],
                   unsigned long long (&mc)[4], unsigned long long (&mn)[4], int ktn){
    const int kb = kt * 64;
    // V(kt) loads issued at phase top (consumed at the end of the phase)
    bf16x8 vf[4][2];
#pragma unroll
    for (int nd = 0; nd < 4; ++nd)
#pragma unroll
      for (int kk = 0; kk < 2; ++kk)
        vf[nd][kk] = *(const bf16x8*)&Vt[hb + (size_t)(nd*16 + l16)*1024 + kb + kk*32 + lg*8];
    // QK^T with current K regs (loaded a full phase ago)
    f32x4 s[4];
    __builtin_amdgcn_s_setprio(1);
#pragma unroll
    for (int nk = 0; nk < 4; ++nk){
      f32x4 t0 = (f32x4){0.f, 0.f, 0.f, 0.f};
      t0 = mfma16(qf0, kc[nk][0], t0);
      t0 = mfma16(qf1, kc[nk][1], t0);
      s[nk] = t0;
    }
    __builtin_amdgcn_s_setprio(0);
    // prefetch next K tile + next mask words into the other register buffer
    KLD(ktn * 64, kn);
    MLD(ktn, mn);
    // max-free masked exp + per-lane partial row sums (mc loaded a phase ago)
    float p[4][4];
#pragma unroll
    for (int nk = 0; nk < 4; ++nk)
#pragma unroll
      for (int r = 0; r < 4; ++r){
        float pen = ((mc[r] >> (nk*16 + l16)) & 1ull) ? -100000.0f : 0.0f;
        p[nk][r] = __expf(s[nk][r] + pen);     // masked -> exp(-1e5) == 0
      }
#pragma unroll
    for (int r = 0; r < 4; ++r) ls[r] += (p[0][r] + p[1][r]) + (p[2][r] + p[3][r]);
    // P -> wave-private LDS (swizzled); wave-local ordering only, no block barrier
    asm volatile("s_waitcnt lgkmcnt(0)" ::: "memory");   // prev-phase P reads retired
    __builtin_amdgcn_sched_barrier(0);
#pragma unroll
    for (int nk = 0; nk < 4; ++nk)
#pragma unroll
      for (int r = 0; r < 4; ++r){
        int row = lg*4 + r;
        int col = (nk*16 + l16) ^ ((row & 7) << 3);
        Pw[row*64 + col] = f2bf(p[nk][r]);
      }
    asm volatile("s_waitcnt lgkmcnt(0)" ::: "memory");   // writes visible before reads
    __builtin_amdgcn_sched_barrier(0);
    // O += P V
    __builtin_amdgcn_s_setprio(1);
#pragma unroll
    for (int kk = 0; kk < 2; ++kk){
      int colg = (kk*32 + lg*8) ^ ((l16 & 7) << 3);
      bf16x8 pf = *(const bf16x8*)&Pw[l16*64 + colg];
#pragma unroll
      for (int nd = 0; nd < 4; ++nd)
        O[nd] = mfma16(pf, vf[nd][kk], O[nd]);
    }
    __builtin_amdgcn_s_setprio(0);
  };

  KLD(0, kA);
  MLD(0, mA);
#pragma unroll 1
  for (int kt2 = 0; kt2 < 8; ++kt2){
    PHASE(2*kt2,     kA, kB, mA, mB, 2*kt2 + 1);
    PHASE(2*kt2 + 1, kB, kA, mB, mA, (2*kt2 + 2) & 15);   // last prefetch wraps (unused)
  }

  // epilogue: reduce row sums across the 16-lane group, normalize, store
#pragma unroll
  for (int r = 0; r < 4; ++r){
    float v = ls[r];
#pragma unroll
    for (int off = 1; off < 16; off <<= 1) v += __shfl_xor(v, off, 64);
    float inv = 1.0f / v;
    int q = q0 + lg*4 + r;
    size_t rowb = ((size_t)q*4 + b)*1024 + h*64;
#pragma unroll
    for (int nd = 0; nd < 4; ++nd)
      AO[rowb + nd*16 + l16] = f2bf(O[nd][r] * inv);
  }
}

extern "C" void kernel_launch(void* const* d_in, const int* in_sizes, int n_in,
                              void* d_out, int out_size, void* d_ws, size_t ws_size,
                              hipStream_t stream)
{
  const float* q   = (const float*)d_in[0];
  const float* k   = (const float*)d_in[1];
  const float* v   = (const float*)d_in[2];
  const int*   kpm = (const int*)d_in[3];
  const int*   am  = (const int*)d_in[4];
  const float* qw  = (const float*)d_in[5];
  const float* kw  = (const float*)d_in[6];
  const float* vw  = (const float*)d_in[7];
  const float* ow  = (const float*)d_in[8];
  unsigned short* ws = (unsigned short*)d_ws;
  unsigned long long* mw = (unsigned long long*)(ws + OFF_MW);

  cvt_all<<<16384, 256, 0, stream>>>(q, k, v, qw, kw, vw, ow, ws);
  pack_mask<<<256, 256, 0, stream>>>(am, kpm, mw);

  dim3 gg(8, 32);
  gemm_bt<<<gg, 256, 0, stream>>>(ws + OFF_XQ, ws + OFF_WQ, nullptr, ws + OFF_QR, 1, 0.125f);
  gemm_bt<<<gg, 256, 0, stream>>>(ws + OFF_XK, ws + OFF_WK, nullptr, ws + OFF_KR, 1, 1.0f);
  gemm_bt<<<gg, 256, 0, stream>>>(ws + OFF_XV, ws + OFF_WV, nullptr, ws + OFF_VROW, 2, 1.0f);
  vtrans<<<dim3(16, 64), 256, 0, stream>>>(ws + OFF_VROW, ws + OFF_VT);
  attn_kernel<<<1024, 256, 0, stream>>>(ws + OFF_QR, ws + OFF_KR, ws + OFF_VT,
                                        mw, ws + OFF_AO);
  gemm_bt<<<gg, 256, 0, stream>>>(ws + OFF_AO, ws + OFF_WO, (float*)d_out, nullptr, 0, 1.0f);
}

// Round 5
// 165.371 us; speedup vs baseline: 1.4987x; 1.4987x over previous
//
#include <hip/hip_runtime.h>
#include <hip/hip_bf16.h>
#include <math.h>

typedef __bf16 bf16x8 __attribute__((ext_vector_type(8)));
typedef float f32x4 __attribute__((ext_vector_type(4)));
typedef unsigned short u16x8 __attribute__((ext_vector_type(8)));
typedef unsigned short u16x4 __attribute__((ext_vector_type(4)));

// ---- problem constants ----
// T=1024, B=4, H=16, D=64, E=1024, M = T*B = 4096 (row m = t*4 + b)

// ws layout, element offsets (ushort elements)
#define OFF_XQ   0u          // 4096x1024 bf16
#define OFF_XK   4194304u
#define OFF_XV   8388608u
#define OFF_WQ   12582912u   // 1024x1024 bf16
#define OFF_WK   13631488u
#define OFF_WV   14680064u
#define OFF_WO   15728640u
#define OFF_QR   16777216u   // [b][h][t][d] bf16 (rope'd, Q pre-scaled by 0.125)
#define OFF_KR   20971520u
#define OFF_VROW 25165824u   // [b][h][t][d] bf16
#define OFF_VT   29360128u   // [b][h][d][t] bf16
#define OFF_AO   33554432u   // [m=q*4+b][e=h*64+d] bf16
#define OFF_MW   37748736u   // 65536 x u64 mask bits (512 KB), 8B aligned

static __device__ __forceinline__ unsigned short f2bf(float f){
  unsigned u = __builtin_bit_cast(unsigned, f);
  u += 0x7FFFu + ((u >> 16) & 1u);           // RNE
  return (unsigned short)(u >> 16);
}

static __device__ __forceinline__ f32x4 mfma16(bf16x8 a, bf16x8 b, f32x4 c){
  return __builtin_amdgcn_mfma_f32_16x16x32_bf16(a, b, c, 0, 0, 0);
}

// async global->LDS, 16B per lane (dest = wave-uniform base + lane*16)
static __device__ __forceinline__ void glds16(const unsigned short* g, unsigned short* l){
  __builtin_amdgcn_global_load_lds(
      (const __attribute__((address_space(1))) unsigned int*)g,
      (__attribute__((address_space(3))) unsigned int*)l, 16, 0, 0);
}

// -------- fp32 -> bf16 conversion of all inputs into ws (contiguous) --------
__global__ __launch_bounds__(256) void cvt_all(
    const float* __restrict__ q, const float* __restrict__ k, const float* __restrict__ v,
    const float* __restrict__ qw, const float* __restrict__ kw, const float* __restrict__ vw,
    const float* __restrict__ ow, unsigned short* __restrict__ ws)
{
  size_t e = ((size_t)blockIdx.x * 256 + threadIdx.x) * 4;
  const float* s;
  if      (e < 4194304u)  { s = q  + e; }
  else if (e < 8388608u)  { s = k  + (e - 4194304u); }
  else if (e < 12582912u) { s = v  + (e - 8388608u); }
  else if (e < 13631488u) { s = qw + (e - 12582912u); }
  else if (e < 14680064u) { s = kw + (e - 13631488u); }
  else if (e < 15728640u) { s = vw + (e - 14680064u); }
  else                    { s = ow + (e - 15728640u); }
  float4 f = *(const float4*)s;
  u16x4 o;
  o[0] = f2bf(f.x); o[1] = f2bf(f.y); o[2] = f2bf(f.z); o[3] = f2bf(f.w);
  *(u16x4*)(ws + e) = o;
}

// -------- pack (am | kpm) into bitmask words: mw[(b*1024+q)*16 + w], bit j = key (w*64+j) masked --------
__global__ __launch_bounds__(256) void pack_mask(
    const int* __restrict__ am, const int* __restrict__ kpm, unsigned long long* __restrict__ mw)
{
  int idx = blockIdx.x * 256 + threadIdx.x;       // 65536 total
  int w = idx & 15, q = (idx >> 4) & 1023, b = idx >> 14;
  const int* ap = am + ((size_t)(b*1024 + q))*1024 + w*64;
  const int* kp = kpm + b*1024 + w*64;
  unsigned long long bits = 0ull;
#pragma unroll
  for (int j = 0; j < 64; j += 4){
    int4 a = *(const int4*)(ap + j);
    int4 c = *(const int4*)(kp + j);
    unsigned long long m =
        (unsigned long long)(((a.x | c.x) != 0) ? 1 : 0)
      | ((unsigned long long)(((a.y | c.y) != 0) ? 1 : 0) << 1)
      | ((unsigned long long)(((a.z | c.z) != 0) ? 1 : 0) << 2)
      | ((unsigned long long)(((a.w | c.w) != 0) ? 1 : 0) << 3);
    bits |= (m << j);
  }
  mw[idx] = bits;
}

// -------- GEMM: C[m][n] = sum_k A[m][k] * W[n][k]   (M=4096, N=1024, K=1024) --------
// 2-ahead glds pipeline, 4 LDS buffers, raw s_barrier + counted vmcnt (T3/T4).
// mode 0: outF fp32; mode 1: RoPE (acc*oscale) -> [b][h][t][d] bf16; mode 2: plain -> [b][h][t][d] bf16
__global__ __launch_bounds__(256) void gemm_bt(
    const unsigned short* __restrict__ A, const unsigned short* __restrict__ W,
    float* __restrict__ outF, unsigned short* __restrict__ outB, int mode, float oscale)
{
  const int tid = threadIdx.x;
  const int lane = tid & 63, wave = tid >> 6;
  const int wr = wave >> 1, wc = wave & 1;
  const int l16 = lane & 15, lg = lane >> 4;
  const int m0 = blockIdx.y * 128, n0 = blockIdx.x * 128;

  __shared__ unsigned short As[4][4096];
  __shared__ unsigned short Bs[4][4096];

  f32x4 acc[4][4];
#pragma unroll
  for (int i = 0; i < 4; ++i)
#pragma unroll
    for (int j = 0; j < 4; ++j)
      acc[i][j] = (f32x4){0.f, 0.f, 0.f, 0.f};

  const int r0 = tid >> 2;           // 0..63
  const int c0 = (tid & 3) * 8;      // 0,8,16,24
  const unsigned short* Ap = A + (size_t)(m0 + r0) * 1024 + c0;
  const unsigned short* Wp = W + (size_t)(n0 + r0) * 1024 + c0;

#define STG(buf, kt) do{ \
    glds16(Ap + (kt)*32,         &As[buf][(size_t)tid*8]); \
    glds16(Ap + 65536 + (kt)*32, &As[buf][2048 + (size_t)tid*8]); \
    glds16(Wp + (kt)*32,         &Bs[buf][(size_t)tid*8]); \
    glds16(Wp + 65536 + (kt)*32, &Bs[buf][2048 + (size_t)tid*8]); }while(0)

  STG(0, 0);
  STG(1, 1);

  for (int kt = 0; kt < 32; ++kt){
    if (kt < 30){
      STG((kt + 2) & 3, kt + 2);
      asm volatile("s_waitcnt vmcnt(8)" ::: "memory");   // tile kt's 4 loads retired
    } else if (kt == 30){
      asm volatile("s_waitcnt vmcnt(4)" ::: "memory");
    } else {
      asm volatile("s_waitcnt vmcnt(0)" ::: "memory");
    }
    __builtin_amdgcn_sched_barrier(0);
    __builtin_amdgcn_s_barrier();                        // all waves' tile-kt loads done
    __builtin_amdgcn_sched_barrier(0);
    const unsigned short* Ab = As[kt & 3];
    const unsigned short* Bb = Bs[kt & 3];
    bf16x8 af[4], bfr[4];
#pragma unroll
    for (int mt = 0; mt < 4; ++mt) af[mt]  = *(const bf16x8*)&Ab[(wr*64 + mt*16 + l16)*32 + lg*8];
#pragma unroll
    for (int nt = 0; nt < 4; ++nt) bfr[nt] = *(const bf16x8*)&Bb[(wc*64 + nt*16 + l16)*32 + lg*8];
#pragma unroll
    for (int mt = 0; mt < 4; ++mt)
#pragma unroll
      for (int nt = 0; nt < 4; ++nt)
        acc[mt][nt] = mfma16(af[mt], bfr[nt], acc[mt][nt]);
  }
#undef STG

  if (mode == 0){
#pragma unroll
    for (int mt = 0; mt < 4; ++mt)
#pragma unroll
      for (int nt = 0; nt < 4; ++nt)
#pragma unroll
        for (int r = 0; r < 4; ++r){
          int m = m0 + wr*64 + mt*16 + lg*4 + r;
          int n = n0 + wc*64 + nt*16 + l16;
          outF[(size_t)m*1024 + n] = acc[mt][nt][r];
        }
  } else if (mode == 2){
#pragma unroll
    for (int mt = 0; mt < 4; ++mt)
#pragma unroll
      for (int nt = 0; nt < 4; ++nt)
#pragma unroll
        for (int r = 0; r < 4; ++r){
          int m = m0 + wr*64 + mt*16 + lg*4 + r;
          int n = n0 + wc*64 + nt*16 + l16;
          int t = m >> 2, bi = m & 3, h = n >> 6, d = n & 63;
          outB[(((size_t)(bi*16 + h))*1024 + t)*64 + d] = f2bf(acc[mt][nt][r]);
        }
  } else { // mode 1: RoPE.  acc pair (nt, nt+2) holds (x1, x2) for d and d+32.
#pragma unroll
    for (int mt = 0; mt < 4; ++mt){
      int mbase = m0 + wr*64 + mt*16 + lg*4;   // multiple of 4 -> b = r, t fixed
      int t = mbase >> 2;
#pragma unroll
      for (int nt = 0; nt < 2; ++nt){
        int n = n0 + wc*64 + nt*16 + l16;
        int h = n >> 6, d = n & 31;
        float theta = expf((float)d * -0.28782313662425575f);  // -ln(10000)/32
        float ang = (float)t * theta;
        float sv = sinf(ang), cv = cosf(ang);
#pragma unroll
        for (int r = 0; r < 4; ++r){
          float x1 = acc[mt][nt][r]     * oscale;
          float x2 = acc[mt][nt + 2][r] * oscale;
          float o1 = x1*cv - x2*sv;
          float o2 = x1*sv + x2*cv;
          size_t ob = (((size_t)(r*16 + h))*1024 + t)*64;   // b = r
          outB[ob + d]      = f2bf(o1);
          outB[ob + d + 32] = f2bf(o2);
        }
      }
    }
  }
}

// -------- V transpose per head: Vrow[b][h][t][d] -> Vt[b][h][d][t] --------
__global__ __launch_bounds__(256) void vtrans(
    const unsigned short* __restrict__ Vrow, unsigned short* __restrict__ Vt)
{
  const int bh = blockIdx.y;
  const int t0 = blockIdx.x * 64;
  const unsigned short* src = Vrow + (size_t)bh*65536 + (size_t)t0*64;
  unsigned short* dst = Vt + (size_t)bh*65536 + t0;
  __shared__ unsigned short tile[64][65];
  const int tid = threadIdx.x;
#pragma unroll
  for (int i = 0; i < 16; ++i){
    int idx = tid + i*256;
    int r = idx >> 6, c = idx & 63;
    tile[r][c] = src[r*64 + c];
  }
  __syncthreads();
#pragma unroll
  for (int i = 0; i < 16; ++i){
    int idx = tid + i*256;
    int d = idx >> 6, c = idx & 63;
    dst[(size_t)d*1024 + c] = tile[c][d];
  }
}

// -------- flash attention v5: 8 waves x 32 q-rows = 256 q-rows/block; K/V staged in LDS
// once per block per phase via global_load_lds (double-buffered, raw s_barrier + counted
// vmcnt). LDS tiles XOR-swizzled on the 16B granule BOTH sides (pre-swizzled glds source
// + swizzled ds_read). Max-free masked softmax; P-LDS roundtrip per wave (swizzled).
// Q pre-scaled by 0.125; mask via bit words mw[(b*1024+q)*16 + kt].
__global__ __launch_bounds__(512, 2) void attn_kernel(
    const unsigned short* __restrict__ Qr, const unsigned short* __restrict__ Kr,
    const unsigned short* __restrict__ Vt, const unsigned long long* __restrict__ mw,
    unsigned short* __restrict__ AO)
{
  const int tid = threadIdx.x;
  const int lane = tid & 63, w = tid >> 6;       // 8 waves
  const int l16 = lane & 15, lg = lane >> 4;
  const int wg = blockIdx.x;                     // 256 blocks
  const int xcd = wg & 7;
  const int bh = xcd * 8 + ((wg >> 3) & 7);      // all 4 q-tiles of a head on one XCD
  const int qt = wg >> 6;                        // 0..3
  const int b = bh >> 4, h = bh & 15;
  const int q0 = qt * 256 + w * 32;              // wave's 32 q-rows
  const size_t hb = (size_t)bh * 65536;
  const unsigned long long* mwp = mw + (size_t)b * 16384 + (size_t)(q0 + lg*4) * 16;

  __shared__ unsigned short Ks[2][4096];   // [64 keys][64 d], 16B-unit swizzled
  __shared__ unsigned short Vs[2][4096];   // [64 d][64 keys], 16B-unit swizzled
  __shared__ unsigned short Plds[8][2048]; // per-wave 32x64
  unsigned short* Pw = Plds[w];

  // staging: thread tid fills LDS linear slot tid*16B = (row=tid>>3, unit=tid&7);
  // source column-unit pre-swizzled so that LDS[row][u] holds global [row][u^(row&7)]
  const int srow = tid >> 3;
  const int scol = (tid & 7) ^ (srow & 7);
  const unsigned short* Ksrc = Kr + hb + (size_t)srow*64   + scol*8;   // + kt*4096
  const unsigned short* Vsrc = Vt + hb + (size_t)srow*1024 + scol*8;   // + kt*64

  // Q fragments (rows q0+mt*16+l16)
  bf16x8 qf[2][2];
#pragma unroll
  for (int mt = 0; mt < 2; ++mt)
#pragma unroll
    for (int kk = 0; kk < 2; ++kk)
      qf[mt][kk] = *(const bf16x8*)&Qr[hb + (size_t)(q0 + mt*16 + l16)*64 + kk*32 + lg*8];

  f32x4 O[2][4];
  float ls[2][4];
#pragma unroll
  for (int mt = 0; mt < 2; ++mt){
#pragma unroll
    for (int nd = 0; nd < 4; ++nd) O[mt][nd] = (f32x4){0.f, 0.f, 0.f, 0.f};
#pragma unroll
    for (int r = 0; r < 4; ++r) ls[mt][r] = 0.f;
  }

  // prologue: stage tile 0 into buffer 0
  glds16(Ksrc, &Ks[0][(size_t)tid*8]);
  glds16(Vsrc, &Vs[0][(size_t)tid*8]);

#pragma unroll 1
  for (int kt = 0; kt < 16; ++kt){
    const int cur = kt & 1;
    if (kt < 15){
      glds16(Ksrc + (kt+1)*4096, &Ks[cur^1][(size_t)tid*8]);
      glds16(Vsrc + (kt+1)*64,   &Vs[cur^1][(size_t)tid*8]);
      asm volatile("s_waitcnt vmcnt(2)" ::: "memory");   // tile kt's 2 loads landed
    } else {
      asm volatile("s_waitcnt vmcnt(0)" ::: "memory");
    }
    __builtin_amdgcn_sched_barrier(0);
    __builtin_amdgcn_s_barrier();                        // tile kt resident for all waves
    __builtin_amdgcn_sched_barrier(0);

    const unsigned short* Kb = Ks[cur];
    const unsigned short* Vb = Vs[cur];

    // mask words for this wave's 32 rows (issued early; L2/L3 latency covered by ds+MFMA)
    unsigned long long bits[2][4];
#pragma unroll
    for (int mt = 0; mt < 2; ++mt)
#pragma unroll
      for (int r = 0; r < 4; ++r)
        bits[mt][r] = mwp[mt*256 + r*16 + kt];

    // K fragments from LDS (swizzled read)
    bf16x8 kf[4][2];
#pragma unroll
    for (int nk = 0; nk < 4; ++nk)
#pragma unroll
      for (int kk = 0; kk < 2; ++kk){
        int row = nk*16 + l16;
        kf[nk][kk] = *(const bf16x8*)&Kb[row*64 + (((kk*4 + lg) ^ (row & 7)) << 3)];
      }

    // QK^T
    f32x4 s[2][4];
    __builtin_amdgcn_s_setprio(1);
#pragma unroll
    for (int nk = 0; nk < 4; ++nk)
#pragma unroll
      for (int mt = 0; mt < 2; ++mt){
        f32x4 t0 = (f32x4){0.f, 0.f, 0.f, 0.f};
        t0 = mfma16(qf[mt][0], kf[nk][0], t0);
        t0 = mfma16(qf[mt][1], kf[nk][1], t0);
        s[mt][nk] = t0;
      }
    __builtin_amdgcn_s_setprio(0);

    // V fragments from LDS (swizzled read) — consumed after the P roundtrip
    bf16x8 vf[4][2];
#pragma unroll
    for (int nd = 0; nd < 4; ++nd)
#pragma unroll
      for (int kk = 0; kk < 2; ++kk){
        int row = nd*16 + l16;
        vf[nd][kk] = *(const bf16x8*)&Vb[row*64 + (((kk*4 + lg) ^ (row & 7)) << 3)];
      }

    // max-free masked exp + per-lane partial row sums
    float p[2][4][4];
#pragma unroll
    for (int mt = 0; mt < 2; ++mt){
#pragma unroll
      for (int nk = 0; nk < 4; ++nk)
#pragma unroll
        for (int r = 0; r < 4; ++r){
          float pen = ((bits[mt][r] >> (nk*16 + l16)) & 1ull) ? -100000.0f : 0.0f;
          p[mt][nk][r] = __expf(s[mt][nk][r] + pen);   // masked -> exactly 0
        }
#pragma unroll
      for (int r = 0; r < 4; ++r)
        ls[mt][r] += (p[mt][0][r] + p[mt][1][r]) + (p[mt][2][r] + p[mt][3][r]);
    }

    // P -> wave-private LDS (swizzled), then read back as A-fragments
#pragma unroll
    for (int mt = 0; mt < 2; ++mt)
#pragma unroll
      for (int nk = 0; nk < 4; ++nk)
#pragma unroll
        for (int r = 0; r < 4; ++r){
          int row = mt*16 + lg*4 + r;
          int col = (nk*16 + l16) ^ ((row & 7) << 3);
          Pw[row*64 + col] = f2bf(p[mt][nk][r]);
        }
    asm volatile("s_waitcnt lgkmcnt(0)" ::: "memory");   // writes visible before reads
    __builtin_amdgcn_sched_barrier(0);

    // O += P V
    __builtin_amdgcn_s_setprio(1);
#pragma unroll
    for (int mt = 0; mt < 2; ++mt)
#pragma unroll
      for (int kk = 0; kk < 2; ++kk){
        int row = mt*16 + l16;
        int colg = (kk*32 + lg*8) ^ ((row & 7) << 3);
        bf16x8 pf = *(const bf16x8*)&Pw[row*64 + colg];
#pragma unroll
        for (int nd = 0; nd < 4; ++nd)
          O[mt][nd] = mfma16(pf, vf[nd][kk], O[mt][nd]);
      }
    __builtin_amdgcn_s_setprio(0);

    __builtin_amdgcn_sched_barrier(0);
    __builtin_amdgcn_s_barrier();        // all waves done reading tile kt before overwrite
    __builtin_amdgcn_sched_barrier(0);
  }

  // epilogue: reduce row sums across the 16-lane group, normalize, store
#pragma unroll
  for (int mt = 0; mt < 2; ++mt)
#pragma unroll
    for (int r = 0; r < 4; ++r){
      float v = ls[mt][r];
#pragma unroll
      for (int off = 1; off < 16; off <<= 1) v += __shfl_xor(v, off, 64);
      float inv = 1.0f / v;
      int q = q0 + mt*16 + lg*4 + r;
      size_t rowb = ((size_t)q*4 + b)*1024 + h*64;
#pragma unroll
      for (int nd = 0; nd < 4; ++nd)
        AO[rowb + nd*16 + l16] = f2bf(O[mt][nd][r] * inv);
    }
}

extern "C" void kernel_launch(void* const* d_in, const int* in_sizes, int n_in,
                              void* d_out, int out_size, void* d_ws, size_t ws_size,
                              hipStream_t stream)
{
  const float* q   = (const float*)d_in[0];
  const float* k   = (const float*)d_in[1];
  const float* v   = (const float*)d_in[2];
  const int*   kpm = (const int*)d_in[3];
  const int*   am  = (const int*)d_in[4];
  const float* qw  = (const float*)d_in[5];
  const float* kw  = (const float*)d_in[6];
  const float* vw  = (const float*)d_in[7];
  const float* ow  = (const float*)d_in[8];
  unsigned short* ws = (unsigned short*)d_ws;
  unsigned long long* mw = (unsigned long long*)(ws + OFF_MW);

  cvt_all<<<16384, 256, 0, stream>>>(q, k, v, qw, kw, vw, ow, ws);
  pack_mask<<<256, 256, 0, stream>>>(am, kpm, mw);

  dim3 gg(8, 32);
  gemm_bt<<<gg, 256, 0, stream>>>(ws + OFF_XQ, ws + OFF_WQ, nullptr, ws + OFF_QR, 1, 0.125f);
  gemm_bt<<<gg, 256, 0, stream>>>(ws + OFF_XK, ws + OFF_WK, nullptr, ws + OFF_KR, 1, 1.0f);
  gemm_bt<<<gg, 256, 0, stream>>>(ws + OFF_XV, ws + OFF_WV, nullptr, ws + OFF_VROW, 2, 1.0f);
  vtrans<<<dim3(16, 64), 256, 0, stream>>>(ws + OFF_VROW, ws + OFF_VT);
  attn_kernel<<<256, 512, 0, stream>>>(ws + OFF_QR, ws + OFF_KR, ws + OFF_VT,
                                       mw, ws + OFF_AO);
  gemm_bt<<<gg, 256, 0, stream>>>(ws + OFF_AO, ws + OFF_WO, (float*)d_out, nullptr, 0, 1.0f);
}

// Round 6
// 149.172 us; speedup vs baseline: 1.6615x; 1.1086x over previous
//
#include <hip/hip_runtime.h>
#include <hip/hip_bf16.h>
#include <math.h>

typedef __bf16 bf16x8 __attribute__((ext_vector_type(8)));
typedef float f32x4 __attribute__((ext_vector_type(4)));
typedef unsigned short u16x8 __attribute__((ext_vector_type(8)));
typedef unsigned short u16x4 __attribute__((ext_vector_type(4)));

// ---- problem constants ----
// T=1024, B=4, H=16, D=64, E=1024, M = T*B = 4096 (row m = t*4 + b)

// ws layout, element offsets (ushort elements)
#define OFF_XQ   0u          // 4096x1024 bf16
#define OFF_XK   4194304u
#define OFF_XV   8388608u
#define OFF_WQ   12582912u   // 1024x1024 bf16
#define OFF_WK   13631488u
#define OFF_WV   14680064u
#define OFF_WO   15728640u
#define OFF_QR   16777216u   // [b][h][t][d] bf16 (rope'd, Q pre-scaled by 0.125)
#define OFF_KR   20971520u
#define OFF_VROW 25165824u   // [b][h][t][d] bf16
#define OFF_VT   29360128u   // [b][h][d][t] bf16
#define OFF_AO   33554432u   // [m=q*4+b][e=h*64+d] bf16
#define OFF_MW   37748736u   // 65536 x u64 mask bits (512 KB), 8B aligned

static __device__ __forceinline__ unsigned short f2bf(float f){
  unsigned u = __builtin_bit_cast(unsigned, f);
  u += 0x7FFFu + ((u >> 16) & 1u);           // RNE
  return (unsigned short)(u >> 16);
}

static __device__ __forceinline__ f32x4 mfma16(bf16x8 a, bf16x8 b, f32x4 c){
  return __builtin_amdgcn_mfma_f32_16x16x32_bf16(a, b, c, 0, 0, 0);
}

// async global->LDS, 16B per lane (dest = wave-uniform base + lane*16)
static __device__ __forceinline__ void glds16(const unsigned short* g, unsigned short* l){
  __builtin_amdgcn_global_load_lds(
      (const __attribute__((address_space(1))) unsigned int*)g,
      (__attribute__((address_space(3))) unsigned int*)l, 16, 0, 0);
}

// -------- fp32 -> bf16 conversion of all inputs into ws (contiguous) --------
__global__ __launch_bounds__(256) void cvt_all(
    const float* __restrict__ q, const float* __restrict__ k, const float* __restrict__ v,
    const float* __restrict__ qw, const float* __restrict__ kw, const float* __restrict__ vw,
    const float* __restrict__ ow, unsigned short* __restrict__ ws)
{
  size_t e = ((size_t)blockIdx.x * 256 + threadIdx.x) * 4;
  const float* s;
  if      (e < 4194304u)  { s = q  + e; }
  else if (e < 8388608u)  { s = k  + (e - 4194304u); }
  else if (e < 12582912u) { s = v  + (e - 8388608u); }
  else if (e < 13631488u) { s = qw + (e - 12582912u); }
  else if (e < 14680064u) { s = kw + (e - 13631488u); }
  else if (e < 15728640u) { s = vw + (e - 14680064u); }
  else                    { s = ow + (e - 15728640u); }
  float4 f = *(const float4*)s;
  u16x4 o;
  o[0] = f2bf(f.x); o[1] = f2bf(f.y); o[2] = f2bf(f.z); o[3] = f2bf(f.w);
  *(u16x4*)(ws + e) = o;
}

// -------- pack (am | kpm) into bitmask words: mw[(b*1024+q)*16 + w], bit j = key (w*64+j) masked --------
__global__ __launch_bounds__(256) void pack_mask(
    const int* __restrict__ am, const int* __restrict__ kpm, unsigned long long* __restrict__ mw)
{
  int idx = blockIdx.x * 256 + threadIdx.x;       // 65536 total
  int w = idx & 15, q = (idx >> 4) & 1023, b = idx >> 14;
  const int* ap = am + ((size_t)(b*1024 + q))*1024 + w*64;
  const int* kp = kpm + b*1024 + w*64;
  unsigned long long bits = 0ull;
#pragma unroll
  for (int j = 0; j < 64; j += 4){
    int4 a = *(const int4*)(ap + j);
    int4 c = *(const int4*)(kp + j);
    unsigned long long m =
        (unsigned long long)(((a.x | c.x) != 0) ? 1 : 0)
      | ((unsigned long long)(((a.y | c.y) != 0) ? 1 : 0) << 1)
      | ((unsigned long long)(((a.z | c.z) != 0) ? 1 : 0) << 2)
      | ((unsigned long long)(((a.w | c.w) != 0) ? 1 : 0) << 3);
    bits |= (m << j);
  }
  mw[idx] = bits;
}

// -------- shared GEMM core: C[m][n] = sum_k A[m][k]*W[n][k], 128x128 tile, BK=32 --------
// 2 LDS buffers (32 KB), 1-ahead glds prefetch, raw s_barrier + counted vmcnt.
// Ap/Wp pre-offset to (m0+r0)*1024 + c0 / (n0+r0)*1024 + c0.
static __device__ __forceinline__ void gemm_core(
    const unsigned short* __restrict__ Ap, const unsigned short* __restrict__ Wp,
    unsigned short (*As)[4096], unsigned short (*Bs)[4096],
    int tid, int wr, int wc, int l16, int lg, f32x4 (&acc)[4][4])
{
  glds16(Ap,         &As[0][(size_t)tid*8]);
  glds16(Ap + 65536, &As[0][2048 + (size_t)tid*8]);
  glds16(Wp,         &Bs[0][(size_t)tid*8]);
  glds16(Wp + 65536, &Bs[0][2048 + (size_t)tid*8]);

  for (int kt = 0; kt < 32; ++kt){
    const int cur = kt & 1;
    if (kt < 31){
      glds16(Ap + (kt+1)*32,         &As[cur^1][(size_t)tid*8]);
      glds16(Ap + 65536 + (kt+1)*32, &As[cur^1][2048 + (size_t)tid*8]);
      glds16(Wp + (kt+1)*32,         &Bs[cur^1][(size_t)tid*8]);
      glds16(Wp + 65536 + (kt+1)*32, &Bs[cur^1][2048 + (size_t)tid*8]);
      asm volatile("s_waitcnt vmcnt(4)" ::: "memory");   // tile kt's 4 loads retired
    } else {
      asm volatile("s_waitcnt vmcnt(0)" ::: "memory");
    }
    __builtin_amdgcn_sched_barrier(0);
    __builtin_amdgcn_s_barrier();                        // tile kt resident for all waves
    __builtin_amdgcn_sched_barrier(0);
    const unsigned short* Ab = As[cur];
    const unsigned short* Bb = Bs[cur];
    bf16x8 af[4], bfr[4];
#pragma unroll
    for (int mt = 0; mt < 4; ++mt) af[mt]  = *(const bf16x8*)&Ab[(wr*64 + mt*16 + l16)*32 + lg*8];
#pragma unroll
    for (int nt = 0; nt < 4; ++nt) bfr[nt] = *(const bf16x8*)&Bb[(wc*64 + nt*16 + l16)*32 + lg*8];
#pragma unroll
    for (int mt = 0; mt < 4; ++mt)
#pragma unroll
      for (int nt = 0; nt < 4; ++nt)
        acc[mt][nt] = mfma16(af[mt], bfr[nt], acc[mt][nt]);
    __builtin_amdgcn_sched_barrier(0);
    __builtin_amdgcn_s_barrier();      // all waves done reading tile kt before overwrite
    __builtin_amdgcn_sched_barrier(0);
  }
}

// -------- fused QKV projection: z=0 Q(RoPE,0.125), z=1 K(RoPE,1.0), z=2 V(plain) --------
__global__ __launch_bounds__(256) void gemm_qkv(unsigned short* __restrict__ ws)
{
  const int tid = threadIdx.x;
  const int lane = tid & 63, wave = tid >> 6;
  const int wr = wave >> 1, wc = wave & 1;
  const int l16 = lane & 15, lg = lane >> 4;
  const int m0 = blockIdx.y * 128, n0 = blockIdx.x * 128;
  const int z = blockIdx.z;

  const unsigned short* A = ws + OFF_XQ + (unsigned)z * 4194304u;
  const unsigned short* W = ws + OFF_WQ + (unsigned)z * 1048576u;

  __shared__ unsigned short As[2][4096];
  __shared__ unsigned short Bs[2][4096];

  f32x4 acc[4][4];
#pragma unroll
  for (int i = 0; i < 4; ++i)
#pragma unroll
    for (int j = 0; j < 4; ++j)
      acc[i][j] = (f32x4){0.f, 0.f, 0.f, 0.f};

  const int r0 = tid >> 2;           // 0..63
  const int c0 = (tid & 3) * 8;      // 0,8,16,24
  gemm_core(A + (size_t)(m0 + r0)*1024 + c0, W + (size_t)(n0 + r0)*1024 + c0,
            As, Bs, tid, wr, wc, l16, lg, acc);

  if (z == 2){   // V: plain bf16 -> [b][h][t][d]
    unsigned short* outB = ws + OFF_VROW;
#pragma unroll
    for (int mt = 0; mt < 4; ++mt)
#pragma unroll
      for (int nt = 0; nt < 4; ++nt)
#pragma unroll
        for (int r = 0; r < 4; ++r){
          int m = m0 + wr*64 + mt*16 + lg*4 + r;
          int n = n0 + wc*64 + nt*16 + l16;
          int t = m >> 2, bi = m & 3, h = n >> 6, d = n & 63;
          outB[(((size_t)(bi*16 + h))*1024 + t)*64 + d] = f2bf(acc[mt][nt][r]);
        }
  } else {       // Q/K: RoPE epilogue. acc pair (nt, nt+2) holds (x1, x2) for d and d+32.
    unsigned short* outB = ws + (z == 0 ? OFF_QR : OFF_KR);
    const float oscale = (z == 0) ? 0.125f : 1.0f;
#pragma unroll
    for (int mt = 0; mt < 4; ++mt){
      int mbase = m0 + wr*64 + mt*16 + lg*4;   // multiple of 4 -> b = r, t fixed
      int t = mbase >> 2;
#pragma unroll
      for (int nt = 0; nt < 2; ++nt){
        int n = n0 + wc*64 + nt*16 + l16;
        int h = n >> 6, d = n & 31;
        float theta = expf((float)d * -0.28782313662425575f);  // -ln(10000)/32
        float ang = (float)t * theta;
        float sv = sinf(ang), cv = cosf(ang);
#pragma unroll
        for (int r = 0; r < 4; ++r){
          float x1 = acc[mt][nt][r]     * oscale;
          float x2 = acc[mt][nt + 2][r] * oscale;
          float o1 = x1*cv - x2*sv;
          float o2 = x1*sv + x2*cv;
          size_t ob = (((size_t)(r*16 + h))*1024 + t)*64;   // b = r
          outB[ob + d]      = f2bf(o1);
          outB[ob + d + 32] = f2bf(o2);
        }
      }
    }
  }
}

// -------- output projection: fp32 out = AO @ WO^T --------
__global__ __launch_bounds__(256) void gemm_o(
    const unsigned short* __restrict__ A, const unsigned short* __restrict__ W,
    float* __restrict__ outF)
{
  const int tid = threadIdx.x;
  const int lane = tid & 63, wave = tid >> 6;
  const int wr = wave >> 1, wc = wave & 1;
  const int l16 = lane & 15, lg = lane >> 4;
  const int m0 = blockIdx.y * 128, n0 = blockIdx.x * 128;

  __shared__ unsigned short As[2][4096];
  __shared__ unsigned short Bs[2][4096];

  f32x4 acc[4][4];
#pragma unroll
  for (int i = 0; i < 4; ++i)
#pragma unroll
    for (int j = 0; j < 4; ++j)
      acc[i][j] = (f32x4){0.f, 0.f, 0.f, 0.f};

  const int r0 = tid >> 2;
  const int c0 = (tid & 3) * 8;
  gemm_core(A + (size_t)(m0 + r0)*1024 + c0, W + (size_t)(n0 + r0)*1024 + c0,
            As, Bs, tid, wr, wc, l16, lg, acc);

#pragma unroll
  for (int mt = 0; mt < 4; ++mt)
#pragma unroll
    for (int nt = 0; nt < 4; ++nt)
#pragma unroll
      for (int r = 0; r < 4; ++r){
        int m = m0 + wr*64 + mt*16 + lg*4 + r;
        int n = n0 + wc*64 + nt*16 + l16;
        outF[(size_t)m*1024 + n] = acc[mt][nt][r];
      }
}

// -------- V transpose per head: Vrow[b][h][t][d] -> Vt[b][h][d][t] --------
__global__ __launch_bounds__(256) void vtrans(
    const unsigned short* __restrict__ Vrow, unsigned short* __restrict__ Vt)
{
  const int bh = blockIdx.y;
  const int t0 = blockIdx.x * 64;
  const unsigned short* src = Vrow + (size_t)bh*65536 + (size_t)t0*64;
  unsigned short* dst = Vt + (size_t)bh*65536 + t0;
  __shared__ unsigned short tile[64][65];
  const int tid = threadIdx.x;
#pragma unroll
  for (int i = 0; i < 16; ++i){
    int idx = tid + i*256;
    int r = idx >> 6, c = idx & 63;
    tile[r][c] = src[r*64 + c];
  }
  __syncthreads();
#pragma unroll
  for (int i = 0; i < 16; ++i){
    int idx = tid + i*256;
    int d = idx >> 6, c = idx & 63;
    dst[(size_t)d*1024 + c] = tile[c][d];
  }
}

// -------- flash attention v6: 8 waves x 16 q-rows = 128 q-rows/block, grid 512 (2 blk/CU);
// K/V staged once per block per phase via global_load_lds (double-buffered, raw s_barrier +
// counted vmcnt); 16B-granule XOR swizzle BOTH sides. Max-free masked softmax.
// Q pre-scaled by 0.125; mask via bit words mw[(b*1024+q)*16 + kt].
__global__ __launch_bounds__(512, 4) void attn_kernel(
    const unsigned short* __restrict__ Qr, const unsigned short* __restrict__ Kr,
    const unsigned short* __restrict__ Vt, const unsigned long long* __restrict__ mw,
    unsigned short* __restrict__ AO)
{
  const int tid = threadIdx.x;
  const int lane = tid & 63, w = tid >> 6;       // 8 waves
  const int l16 = lane & 15, lg = lane >> 4;
  const int wg = blockIdx.x;                     // 512 blocks
  const int xcd = wg & 7;
  const int bh = xcd * 8 + ((wg >> 3) & 7);      // all 8 q-tiles of a head on one XCD
  const int qt = wg >> 6;                        // 0..7
  const int b = bh >> 4, h = bh & 15;
  const int q0 = qt * 128 + w * 16;              // wave's 16 q-rows
  const size_t hb = (size_t)bh * 65536;
  const unsigned long long* mwp = mw + (size_t)b * 16384 + (size_t)(q0 + lg*4) * 16;

  __shared__ unsigned short Ks[2][4096];   // [64 keys][64 d], 16B-unit swizzled
  __shared__ unsigned short Vs[2][4096];   // [64 d][64 keys], 16B-unit swizzled
  __shared__ unsigned short Plds[8][1024]; // per-wave 16x64
  unsigned short* Pw = Plds[w];

  // staging: thread tid fills LDS linear slot tid*16B = (row=tid>>3, unit=tid&7);
  // source column-unit pre-swizzled so that LDS[row][u] holds global [row][u^(row&7)]
  const int srow = tid >> 3;
  const int scol = (tid & 7) ^ (srow & 7);
  const unsigned short* Ksrc = Kr + hb + (size_t)srow*64   + scol*8;   // + kt*4096
  const unsigned short* Vsrc = Vt + hb + (size_t)srow*1024 + scol*8;   // + kt*64

  // Q fragments (rows q0 + l16)
  bf16x8 qf0 = *(const bf16x8*)&Qr[hb + (size_t)(q0 + l16)*64 + lg*8];
  bf16x8 qf1 = *(const bf16x8*)&Qr[hb + (size_t)(q0 + l16)*64 + 32 + lg*8];

  f32x4 O[4];
  float ls[4] = {0.f, 0.f, 0.f, 0.f};
#pragma unroll
  for (int nd = 0; nd < 4; ++nd) O[nd] = (f32x4){0.f, 0.f, 0.f, 0.f};

  // prologue: stage tile 0 into buffer 0
  glds16(Ksrc, &Ks[0][(size_t)tid*8]);
  glds16(Vsrc, &Vs[0][(size_t)tid*8]);

#pragma unroll 1
  for (int kt = 0; kt < 16; ++kt){
    const int cur = kt & 1;
    if (kt < 15){
      glds16(Ksrc + (kt+1)*4096, &Ks[cur^1][(size_t)tid*8]);
      glds16(Vsrc + (kt+1)*64,   &Vs[cur^1][(size_t)tid*8]);
      asm volatile("s_waitcnt vmcnt(2)" ::: "memory");   // tile kt's 2 loads landed
    } else {
      asm volatile("s_waitcnt vmcnt(0)" ::: "memory");
    }
    __builtin_amdgcn_sched_barrier(0);
    __builtin_amdgcn_s_barrier();                        // tile kt resident for all waves
    __builtin_amdgcn_sched_barrier(0);

    const unsigned short* Kb = Ks[cur];
    const unsigned short* Vb = Vs[cur];

    // mask words for this wave's 16 rows
    unsigned long long bits[4];
#pragma unroll
    for (int r = 0; r < 4; ++r) bits[r] = mwp[r*16 + kt];

    // K fragments from LDS (swizzled read)
    bf16x8 kf[4][2];
#pragma unroll
    for (int nk = 0; nk < 4; ++nk)
#pragma unroll
      for (int kk = 0; kk < 2; ++kk){
        int row = nk*16 + l16;
        kf[nk][kk] = *(const bf16x8*)&Kb[row*64 + (((kk*4 + lg) ^ (row & 7)) << 3)];
      }

    // QK^T
    f32x4 s[4];
    __builtin_amdgcn_s_setprio(1);
#pragma unroll
    for (int nk = 0; nk < 4; ++nk){
      f32x4 t0 = (f32x4){0.f, 0.f, 0.f, 0.f};
      t0 = mfma16(qf0, kf[nk][0], t0);
      t0 = mfma16(qf1, kf[nk][1], t0);
      s[nk] = t0;
    }
    __builtin_amdgcn_s_setprio(0);

    // V fragments from LDS (swizzled read) — consumed after the P roundtrip
    bf16x8 vf[4][2];
#pragma unroll
    for (int nd = 0; nd < 4; ++nd)
#pragma unroll
      for (int kk = 0; kk < 2; ++kk){
        int row = nd*16 + l16;
        vf[nd][kk] = *(const bf16x8*)&Vb[row*64 + (((kk*4 + lg) ^ (row & 7)) << 3)];
      }

    // max-free masked exp + per-lane partial row sums
    float p[4][4];
#pragma unroll
    for (int nk = 0; nk < 4; ++nk)
#pragma unroll
      for (int r = 0; r < 4; ++r){
        float pen = ((bits[r] >> (nk*16 + l16)) & 1ull) ? -100000.0f : 0.0f;
        p[nk][r] = __expf(s[nk][r] + pen);   // masked -> exactly 0
      }
#pragma unroll
    for (int r = 0; r < 4; ++r)
      ls[r] += (p[0][r] + p[1][r]) + (p[2][r] + p[3][r]);

    // P -> wave-private LDS (swizzled), then read back as A-fragments
#pragma unroll
    for (int nk = 0; nk < 4; ++nk)
#pragma unroll
      for (int r = 0; r < 4; ++r){
        int row = lg*4 + r;
        int col = (nk*16 + l16) ^ ((row & 7) << 3);
        Pw[row*64 + col] = f2bf(p[nk][r]);
      }
    asm volatile("s_waitcnt lgkmcnt(0)" ::: "memory");   // writes visible before reads
    __builtin_amdgcn_sched_barrier(0);

    // O += P V
    __builtin_amdgcn_s_setprio(1);
#pragma unroll
    for (int kk = 0; kk < 2; ++kk){
      int row = l16;
      int colg = (kk*32 + lg*8) ^ ((row & 7) << 3);
      bf16x8 pf = *(const bf16x8*)&Pw[row*64 + colg];
#pragma unroll
      for (int nd = 0; nd < 4; ++nd)
        O[nd] = mfma16(pf, vf[nd][kk], O[nd]);
    }
    __builtin_amdgcn_s_setprio(0);

    __builtin_amdgcn_sched_barrier(0);
    __builtin_amdgcn_s_barrier();        // all waves done reading tile kt before overwrite
    __builtin_amdgcn_sched_barrier(0);
  }

  // epilogue: reduce row sums across the 16-lane group, normalize, store
#pragma unroll
  for (int r = 0; r < 4; ++r){
    float v = ls[r];
#pragma unroll
    for (int off = 1; off < 16; off <<= 1) v += __shfl_xor(v, off, 64);
    float inv = 1.0f / v;
    int q = q0 + lg*4 + r;
    size_t rowb = ((size_t)q*4 + b)*1024 + h*64;
#pragma unroll
    for (int nd = 0; nd < 4; ++nd)
      AO[rowb + nd*16 + l16] = f2bf(O[nd][r] * inv);
  }
}

extern "C" void kernel_launch(void* const* d_in, const int* in_sizes, int n_in,
                              void* d_out, int out_size, void* d_ws, size_t ws_size,
                              hipStream_t stream)
{
  const float* q   = (const float*)d_in[0];
  const float* k   = (const float*)d_in[1];
  const float* v   = (const float*)d_in[2];
  const int*   kpm = (const int*)d_in[3];
  const int*   am  = (const int*)d_in[4];
  const float* qw  = (const float*)d_in[5];
  const float* kw  = (const float*)d_in[6];
  const float* vw  = (const float*)d_in[7];
  const float* ow  = (const float*)d_in[8];
  unsigned short* ws = (unsigned short*)d_ws;
  unsigned long long* mw = (unsigned long long*)(ws + OFF_MW);

  cvt_all<<<16384, 256, 0, stream>>>(q, k, v, qw, kw, vw, ow, ws);
  pack_mask<<<256, 256, 0, stream>>>(am, kpm, mw);

  gemm_qkv<<<dim3(8, 32, 3), 256, 0, stream>>>(ws);
  vtrans<<<dim3(16, 64), 256, 0, stream>>>(ws + OFF_VROW, ws + OFF_VT);
  attn_kernel<<<512, 512, 0, stream>>>(ws + OFF_QR, ws + OFF_KR, ws + OFF_VT,
                                       mw, ws + OFF_AO);
  gemm_o<<<dim3(8, 32), 256, 0, stream>>>(ws + OFF_AO, ws + OFF_WO, (float*)d_out);
}

// Round 7
// 126.609 us; speedup vs baseline: 1.9576x; 1.1782x over previous
//
#include <hip/hip_runtime.h>
#include <hip/hip_bf16.h>
#include <math.h>

typedef __bf16 bf16x8 __attribute__((ext_vector_type(8)));
typedef float f32x4 __attribute__((ext_vector_type(4)));
typedef unsigned short u16x8 __attribute__((ext_vector_type(8)));
typedef unsigned short u16x4 __attribute__((ext_vector_type(4)));

// ---- problem constants ----
// T=1024, B=4, H=16, D=64, E=1024, M = T*B = 4096 (row m = t*4 + b)

// ws layout, element offsets (ushort elements)
#define OFF_XQ   0u          // 4096x1024 bf16
#define OFF_XK   4194304u
#define OFF_XV   8388608u
#define OFF_WQ   12582912u   // 1024x1024 bf16
#define OFF_WK   13631488u
#define OFF_WV   14680064u
#define OFF_WO   15728640u
#define OFF_QR   16777216u   // [b][h][t][d] bf16 (rope'd, Q pre-scaled by 0.125)
#define OFF_KR   20971520u
#define OFF_VROW 25165824u   // [b][h][t][d] bf16
#define OFF_VT   29360128u   // [b][h][d][t] bf16
#define OFF_AO   33554432u   // [m=q*4+b][e=h*64+d] bf16
#define OFF_MW   37748736u   // 65536 x u64 mask bits (512 KB), 8B aligned

static __device__ __forceinline__ unsigned short f2bf(float f){
  unsigned u = __builtin_bit_cast(unsigned, f);
  u += 0x7FFFu + ((u >> 16) & 1u);           // RNE
  return (unsigned short)(u >> 16);
}

static __device__ __forceinline__ f32x4 mfma16(bf16x8 a, bf16x8 b, f32x4 c){
  return __builtin_amdgcn_mfma_f32_16x16x32_bf16(a, b, c, 0, 0, 0);
}

// async global->LDS, 16B per lane (dest = wave-uniform base + lane*16)
static __device__ __forceinline__ void glds16(const unsigned short* g, unsigned short* l){
  __builtin_amdgcn_global_load_lds(
      (const __attribute__((address_space(1))) unsigned int*)g,
      (__attribute__((address_space(3))) unsigned int*)l, 16, 0, 0);
}

// -------- fp32 -> bf16 conversion of all inputs into ws (contiguous) --------
__global__ __launch_bounds__(256) void cvt_all(
    const float* __restrict__ q, const float* __restrict__ k, const float* __restrict__ v,
    const float* __restrict__ qw, const float* __restrict__ kw, const float* __restrict__ vw,
    const float* __restrict__ ow, unsigned short* __restrict__ ws)
{
  size_t e = ((size_t)blockIdx.x * 256 + threadIdx.x) * 4;
  const float* s;
  if      (e < 4194304u)  { s = q  + e; }
  else if (e < 8388608u)  { s = k  + (e - 4194304u); }
  else if (e < 12582912u) { s = v  + (e - 8388608u); }
  else if (e < 13631488u) { s = qw + (e - 12582912u); }
  else if (e < 14680064u) { s = kw + (e - 13631488u); }
  else if (e < 15728640u) { s = vw + (e - 14680064u); }
  else                    { s = ow + (e - 15728640u); }
  float4 f = *(const float4*)s;
  u16x4 o;
  o[0] = f2bf(f.x); o[1] = f2bf(f.y); o[2] = f2bf(f.z); o[3] = f2bf(f.w);
  *(u16x4*)(ws + e) = o;
}

// -------- pack (am | kpm) into bitmask words: mw[(b*1024+q)*16 + w], bit j = key (w*64+j) masked --------
__global__ __launch_bounds__(256) void pack_mask(
    const int* __restrict__ am, const int* __restrict__ kpm, unsigned long long* __restrict__ mw)
{
  int idx = blockIdx.x * 256 + threadIdx.x;       // 65536 total
  int w = idx & 15, q = (idx >> 4) & 1023, b = idx >> 14;
  const int* ap = am + ((size_t)(b*1024 + q))*1024 + w*64;
  const int* kp = kpm + b*1024 + w*64;
  unsigned long long bits = 0ull;
#pragma unroll
  for (int j = 0; j < 64; j += 4){
    int4 a = *(const int4*)(ap + j);
    int4 c = *(const int4*)(kp + j);
    unsigned long long m =
        (unsigned long long)(((a.x | c.x) != 0) ? 1 : 0)
      | ((unsigned long long)(((a.y | c.y) != 0) ? 1 : 0) << 1)
      | ((unsigned long long)(((a.z | c.z) != 0) ? 1 : 0) << 2)
      | ((unsigned long long)(((a.w | c.w) != 0) ? 1 : 0) << 3);
    bits |= (m << j);
  }
  mw[idx] = bits;
}

// -------- shared GEMM core: C[m][n] = sum_k A[m][k]*W[n][k], 128x128 tile, BK=32 --------
// 2 LDS buffers (32 KB), 1-ahead glds prefetch, raw s_barrier + counted vmcnt.
// LDS 16B-unit XOR-swizzled BOTH sides: LDS[row][u] = G[row][u ^ (row&3) ^ ((row>>2)&3)].
// Callers pre-offset Ap/Wp to (m0+r0)*1024 + c0 with the pre-swizzled c0.
static __device__ __forceinline__ void gemm_core(
    const unsigned short* __restrict__ Ap, const unsigned short* __restrict__ Wp,
    unsigned short (*As)[4096], unsigned short (*Bs)[4096],
    int tid, int wr, int wc, int l16, int lg, f32x4 (&acc)[4][4])
{
  const int su = (lg ^ (l16 & 3) ^ (l16 >> 2)) & 3;   // read-side swizzled unit

  glds16(Ap,         &As[0][(size_t)tid*8]);
  glds16(Ap + 65536, &As[0][2048 + (size_t)tid*8]);
  glds16(Wp,         &Bs[0][(size_t)tid*8]);
  glds16(Wp + 65536, &Bs[0][2048 + (size_t)tid*8]);

  for (int kt = 0; kt < 32; ++kt){
    const int cur = kt & 1;
    if (kt < 31){
      glds16(Ap + (kt+1)*32,         &As[cur^1][(size_t)tid*8]);
      glds16(Ap + 65536 + (kt+1)*32, &As[cur^1][2048 + (size_t)tid*8]);
      glds16(Wp + (kt+1)*32,         &Bs[cur^1][(size_t)tid*8]);
      glds16(Wp + 65536 + (kt+1)*32, &Bs[cur^1][2048 + (size_t)tid*8]);
      asm volatile("s_waitcnt vmcnt(4)" ::: "memory");   // tile kt's 4 loads retired
    } else {
      asm volatile("s_waitcnt vmcnt(0)" ::: "memory");
    }
    __builtin_amdgcn_sched_barrier(0);
    __builtin_amdgcn_s_barrier();                        // tile kt resident for all waves
    __builtin_amdgcn_sched_barrier(0);
    const unsigned short* Ab = As[cur];
    const unsigned short* Bb = Bs[cur];
    bf16x8 af[4], bfr[4];
#pragma unroll
    for (int mt = 0; mt < 4; ++mt) af[mt]  = *(const bf16x8*)&Ab[(wr*64 + mt*16 + l16)*32 + su*8];
#pragma unroll
    for (int nt = 0; nt < 4; ++nt) bfr[nt] = *(const bf16x8*)&Bb[(wc*64 + nt*16 + l16)*32 + su*8];
#pragma unroll
    for (int mt = 0; mt < 4; ++mt)
#pragma unroll
      for (int nt = 0; nt < 4; ++nt)
        acc[mt][nt] = mfma16(af[mt], bfr[nt], acc[mt][nt]);
    __builtin_amdgcn_sched_barrier(0);
    __builtin_amdgcn_s_barrier();      // all waves done reading tile kt before overwrite
    __builtin_amdgcn_sched_barrier(0);
  }
}

// XCD-chunked tile map: each XCD owns 4 contiguous m-panels x all 8 n-panels
// (per-XCD L2 working set = 1 MB A-panel + 2 MB W).
static __device__ __forceinline__ void tile_map(int bx, int by, int& m0, int& n0){
  const int lin = bx + (by << 3);
  const int xcd = lin & 7, j = lin >> 3;
  m0 = ((xcd << 2) + (j >> 3)) * 128;
  n0 = (j & 7) * 128;
}

// -------- fused QKV projection: z=0 Q(RoPE,0.125), z=1 K(RoPE,1.0), z=2 V(plain) --------
__global__ __launch_bounds__(256) void gemm_qkv(unsigned short* __restrict__ ws)
{
  const int tid = threadIdx.x;
  const int lane = tid & 63, wave = tid >> 6;
  const int wr = wave >> 1, wc = wave & 1;
  const int l16 = lane & 15, lg = lane >> 4;
  int m0, n0;
  tile_map(blockIdx.x, blockIdx.y, m0, n0);
  const int z = blockIdx.z;

  const unsigned short* A = ws + OFF_XQ + (unsigned)z * 4194304u;
  const unsigned short* W = ws + OFF_WQ + (unsigned)z * 1048576u;

  __shared__ unsigned short As[2][4096];
  __shared__ unsigned short Bs[2][4096];

  f32x4 acc[4][4];
#pragma unroll
  for (int i = 0; i < 4; ++i)
#pragma unroll
    for (int j = 0; j < 4; ++j)
      acc[i][j] = (f32x4){0.f, 0.f, 0.f, 0.f};

  const int r0 = tid >> 2;                                  // 0..63
  const int c0 = (((tid & 3) ^ (r0 & 3) ^ ((r0 >> 2) & 3)) << 3);   // pre-swizzled source unit
  gemm_core(A + (size_t)(m0 + r0)*1024 + c0, W + (size_t)(n0 + r0)*1024 + c0,
            As, Bs, tid, wr, wc, l16, lg, acc);

  if (z == 2){   // V: plain bf16 -> [b][h][t][d]
    unsigned short* outB = ws + OFF_VROW;
#pragma unroll
    for (int mt = 0; mt < 4; ++mt)
#pragma unroll
      for (int nt = 0; nt < 4; ++nt)
#pragma unroll
        for (int r = 0; r < 4; ++r){
          int m = m0 + wr*64 + mt*16 + lg*4 + r;
          int n = n0 + wc*64 + nt*16 + l16;
          int t = m >> 2, bi = m & 3, h = n >> 6, d = n & 63;
          outB[(((size_t)(bi*16 + h))*1024 + t)*64 + d] = f2bf(acc[mt][nt][r]);
        }
  } else {       // Q/K: RoPE epilogue. acc pair (nt, nt+2) holds (x1, x2) for d and d+32.
    unsigned short* outB = ws + (z == 0 ? OFF_QR : OFF_KR);
    const float oscale = (z == 0) ? 0.125f : 1.0f;
#pragma unroll
    for (int mt = 0; mt < 4; ++mt){
      int mbase = m0 + wr*64 + mt*16 + lg*4;   // multiple of 4 -> b = r, t fixed
      int t = mbase >> 2;
#pragma unroll
      for (int nt = 0; nt < 2; ++nt){
        int n = n0 + wc*64 + nt*16 + l16;
        int h = n >> 6, d = n & 31;
        float theta = expf((float)d * -0.28782313662425575f);  // -ln(10000)/32
        float ang = (float)t * theta;
        float sv = sinf(ang), cv = cosf(ang);
#pragma unroll
        for (int r = 0; r < 4; ++r){
          float x1 = acc[mt][nt][r]     * oscale;
          float x2 = acc[mt][nt + 2][r] * oscale;
          float o1 = x1*cv - x2*sv;
          float o2 = x1*sv + x2*cv;
          size_t ob = (((size_t)(r*16 + h))*1024 + t)*64;   // b = r
          outB[ob + d]      = f2bf(o1);
          outB[ob + d + 32] = f2bf(o2);
        }
      }
    }
  }
}

// -------- output projection: fp32 out = AO @ WO^T --------
__global__ __launch_bounds__(256) void gemm_o(
    const unsigned short* __restrict__ A, const unsigned short* __restrict__ W,
    float* __restrict__ outF)
{
  const int tid = threadIdx.x;
  const int lane = tid & 63, wave = tid >> 6;
  const int wr = wave >> 1, wc = wave & 1;
  const int l16 = lane & 15, lg = lane >> 4;
  int m0, n0;
  tile_map(blockIdx.x, blockIdx.y, m0, n0);

  __shared__ unsigned short As[2][4096];
  __shared__ unsigned short Bs[2][4096];

  f32x4 acc[4][4];
#pragma unroll
  for (int i = 0; i < 4; ++i)
#pragma unroll
    for (int j = 0; j < 4; ++j)
      acc[i][j] = (f32x4){0.f, 0.f, 0.f, 0.f};

  const int r0 = tid >> 2;
  const int c0 = (((tid & 3) ^ (r0 & 3) ^ ((r0 >> 2) & 3)) << 3);
  gemm_core(A + (size_t)(m0 + r0)*1024 + c0, W + (size_t)(n0 + r0)*1024 + c0,
            As, Bs, tid, wr, wc, l16, lg, acc);

#pragma unroll
  for (int mt = 0; mt < 4; ++mt)
#pragma unroll
    for (int nt = 0; nt < 4; ++nt)
#pragma unroll
      for (int r = 0; r < 4; ++r){
        int m = m0 + wr*64 + mt*16 + lg*4 + r;
        int n = n0 + wc*64 + nt*16 + l16;
        outF[(size_t)m*1024 + n] = acc[mt][nt][r];
      }
}

// -------- V transpose per head: Vrow[b][h][t][d] -> Vt[b][h][d][t] --------
__global__ __launch_bounds__(256) void vtrans(
    const unsigned short* __restrict__ Vrow, unsigned short* __restrict__ Vt)
{
  const int bh = blockIdx.y;
  const int t0 = blockIdx.x * 64;
  const unsigned short* src = Vrow + (size_t)bh*65536 + (size_t)t0*64;
  unsigned short* dst = Vt + (size_t)bh*65536 + t0;
  __shared__ unsigned short tile[64][65];
  const int tid = threadIdx.x;
#pragma unroll
  for (int i = 0; i < 16; ++i){
    int idx = tid + i*256;
    int r = idx >> 6, c = idx & 63;
    tile[r][c] = src[r*64 + c];
  }
  __syncthreads();
#pragma unroll
  for (int i = 0; i < 16; ++i){
    int idx = tid + i*256;
    int d = idx >> 6, c = idx & 63;
    dst[(size_t)d*1024 + c] = tile[c][d];
  }
}

// -------- flash attention v6: 8 waves x 16 q-rows = 128 q-rows/block, grid 512 (2 blk/CU);
// K/V staged once per block per phase via global_load_lds (double-buffered, raw s_barrier +
// counted vmcnt); 16B-granule XOR swizzle BOTH sides. Max-free masked softmax.
// Q pre-scaled by 0.125; mask via bit words mw[(b*1024+q)*16 + kt].
__global__ __launch_bounds__(512, 4) void attn_kernel(
    const unsigned short* __restrict__ Qr, const unsigned short* __restrict__ Kr,
    const unsigned short* __restrict__ Vt, const unsigned long long* __restrict__ mw,
    unsigned short* __restrict__ AO)
{
  const int tid = threadIdx.x;
  const int lane = tid & 63, w = tid >> 6;       // 8 waves
  const int l16 = lane & 15, lg = lane >> 4;
  const int wg = blockIdx.x;                     // 512 blocks
  const int xcd = wg & 7;
  const int bh = xcd * 8 + ((wg >> 3) & 7);      // all 8 q-tiles of a head on one XCD
  const int qt = wg >> 6;                        // 0..7
  const int b = bh >> 4, h = bh & 15;
  const int q0 = qt * 128 + w * 16;              // wave's 16 q-rows
  const size_t hb = (size_t)bh * 65536;
  const unsigned long long* mwp = mw + (size_t)b * 16384 + (size_t)(q0 + lg*4) * 16;

  __shared__ unsigned short Ks[2][4096];   // [64 keys][64 d], 16B-unit swizzled
  __shared__ unsigned short Vs[2][4096];   // [64 d][64 keys], 16B-unit swizzled
  __shared__ unsigned short Plds[8][1024]; // per-wave 16x64
  unsigned short* Pw = Plds[w];

  // staging: thread tid fills LDS linear slot tid*16B = (row=tid>>3, unit=tid&7);
  // source column-unit pre-swizzled so that LDS[row][u] holds global [row][u^(row&7)]
  const int srow = tid >> 3;
  const int scol = (tid & 7) ^ (srow & 7);
  const unsigned short* Ksrc = Kr + hb + (size_t)srow*64   + scol*8;   // + kt*4096
  const unsigned short* Vsrc = Vt + hb + (size_t)srow*1024 + scol*8;   // + kt*64

  // Q fragments (rows q0 + l16)
  bf16x8 qf0 = *(const bf16x8*)&Qr[hb + (size_t)(q0 + l16)*64 + lg*8];
  bf16x8 qf1 = *(const bf16x8*)&Qr[hb + (size_t)(q0 + l16)*64 + 32 + lg*8];

  f32x4 O[4];
  float ls[4] = {0.f, 0.f, 0.f, 0.f};
#pragma unroll
  for (int nd = 0; nd < 4; ++nd) O[nd] = (f32x4){0.f, 0.f, 0.f, 0.f};

  // prologue: stage tile 0 into buffer 0
  glds16(Ksrc, &Ks[0][(size_t)tid*8]);
  glds16(Vsrc, &Vs[0][(size_t)tid*8]);

#pragma unroll 1
  for (int kt = 0; kt < 16; ++kt){
    const int cur = kt & 1;
    if (kt < 15){
      glds16(Ksrc + (kt+1)*4096, &Ks[cur^1][(size_t)tid*8]);
      glds16(Vsrc + (kt+1)*64,   &Vs[cur^1][(size_t)tid*8]);
      asm volatile("s_waitcnt vmcnt(2)" ::: "memory");   // tile kt's 2 loads landed
    } else {
      asm volatile("s_waitcnt vmcnt(0)" ::: "memory");
    }
    __builtin_amdgcn_sched_barrier(0);
    __builtin_amdgcn_s_barrier();                        // tile kt resident for all waves
    __builtin_amdgcn_sched_barrier(0);

    const unsigned short* Kb = Ks[cur];
    const unsigned short* Vb = Vs[cur];

    // mask words for this wave's 16 rows
    unsigned long long bits[4];
#pragma unroll
    for (int r = 0; r < 4; ++r) bits[r] = mwp[r*16 + kt];

    // K fragments from LDS (swizzled read)
    bf16x8 kf[4][2];
#pragma unroll
    for (int nk = 0; nk < 4; ++nk)
#pragma unroll
      for (int kk = 0; kk < 2; ++kk){
        int row = nk*16 + l16;
        kf[nk][kk] = *(const bf16x8*)&Kb[row*64 + (((kk*4 + lg) ^ (row & 7)) << 3)];
      }

    // QK^T
    f32x4 s[4];
    __builtin_amdgcn_s_setprio(1);
#pragma unroll
    for (int nk = 0; nk < 4; ++nk){
      f32x4 t0 = (f32x4){0.f, 0.f, 0.f, 0.f};
      t0 = mfma16(qf0, kf[nk][0], t0);
      t0 = mfma16(qf1, kf[nk][1], t0);
      s[nk] = t0;
    }
    __builtin_amdgcn_s_setprio(0);

    // V fragments from LDS (swizzled read) — consumed after the P roundtrip
    bf16x8 vf[4][2];
#pragma unroll
    for (int nd = 0; nd < 4; ++nd)
#pragma unroll
      for (int kk = 0; kk < 2; ++kk){
        int row = nd*16 + l16;
        vf[nd][kk] = *(const bf16x8*)&Vb[row*64 + (((kk*4 + lg) ^ (row & 7)) << 3)];
      }

    // max-free masked exp + per-lane partial row sums
    float p[4][4];
#pragma unroll
    for (int nk = 0; nk < 4; ++nk)
#pragma unroll
      for (int r = 0; r < 4; ++r){
        float pen = ((bits[r] >> (nk*16 + l16)) & 1ull) ? -100000.0f : 0.0f;
        p[nk][r] = __expf(s[nk][r] + pen);   // masked -> exactly 0
      }
#pragma unroll
    for (int r = 0; r < 4; ++r)
      ls[r] += (p[0][r] + p[1][r]) + (p[2][r] + p[3][r]);

    // P -> wave-private LDS (swizzled), then read back as A-fragments
#pragma unroll
    for (int nk = 0; nk < 4; ++nk)
#pragma unroll
      for (int r = 0; r < 4; ++r){
        int row = lg*4 + r;
        int col = (nk*16 + l16) ^ ((row & 7) << 3);
        Pw[row*64 + col] = f2bf(p[nk][r]);
      }
    asm volatile("s_waitcnt lgkmcnt(0)" ::: "memory");   // writes visible before reads
    __builtin_amdgcn_sched_barrier(0);

    // O += P V
    __builtin_amdgcn_s_setprio(1);
#pragma unroll
    for (int kk = 0; kk < 2; ++kk){
      int row = l16;
      int colg = (kk*32 + lg*8) ^ ((row & 7) << 3);
      bf16x8 pf = *(const bf16x8*)&Pw[row*64 + colg];
#pragma unroll
      for (int nd = 0; nd < 4; ++nd)
        O[nd] = mfma16(pf, vf[nd][kk], O[nd]);
    }
    __builtin_amdgcn_s_setprio(0);

    __builtin_amdgcn_sched_barrier(0);
    __builtin_amdgcn_s_barrier();        // all waves done reading tile kt before overwrite
    __builtin_amdgcn_sched_barrier(0);
  }

  // epilogue: reduce row sums across the 16-lane group, normalize, store
#pragma unroll
  for (int r = 0; r < 4; ++r){
    float v = ls[r];
#pragma unroll
    for (int off = 1; off < 16; off <<= 1) v += __shfl_xor(v, off, 64);
    float inv = 1.0f / v;
    int q = q0 + lg*4 + r;
    size_t rowb = ((size_t)q*4 + b)*1024 + h*64;
#pragma unroll
    for (int nd = 0; nd < 4; ++nd)
      AO[rowb + nd*16 + l16] = f2bf(O[nd][r] * inv);
  }
}

extern "C" void kernel_launch(void* const* d_in, const int* in_sizes, int n_in,
                              void* d_out, int out_size, void* d_ws, size_t ws_size,
                              hipStream_t stream)
{
  const float* q   = (const float*)d_in[0];
  const float* k   = (const float*)d_in[1];
  const float* v   = (const float*)d_in[2];
  const int*   kpm = (const int*)d_in[3];
  const int*   am  = (const int*)d_in[4];
  const float* qw  = (const float*)d_in[5];
  const float* kw  = (const float*)d_in[6];
  const float* vw  = (const float*)d_in[7];
  const float* ow  = (const float*)d_in[8];
  unsigned short* ws = (unsigned short*)d_ws;
  unsigned long long* mw = (unsigned long long*)(ws + OFF_MW);

  cvt_all<<<16384, 256, 0, stream>>>(q, k, v, qw, kw, vw, ow, ws);
  pack_mask<<<256, 256, 0, stream>>>(am, kpm, mw);

  gemm_qkv<<<dim3(8, 32, 3), 256, 0, stream>>>(ws);
  vtrans<<<dim3(16, 64), 256, 0, stream>>>(ws + OFF_VROW, ws + OFF_VT);
  attn_kernel<<<512, 512, 0, stream>>>(ws + OFF_QR, ws + OFF_KR, ws + OFF_VT,
                                       mw, ws + OFF_AO);
  gemm_o<<<dim3(8, 32), 256, 0, stream>>>(ws + OFF_AO, ws + OFF_WO, (float*)d_out);
}